// Round 10
// baseline (138.180 us; speedup 1.0000x reference)
//
#include <hip/hip_runtime.h>

// RelativeAttentionPositions: out[b,h,s,t] = dot(tensor[b,h,s,:], E[clip(t-s,-128,128)+128,:]) + bias[h]
// B=4 H=16 S=1024 D=64 MAX_REL=128 VOCAB=257.
// v10 = v9 + DIAGNOSTIC: expand phase executed 3 identical times (idempotent,
// deterministic). Purpose: push our dispatch into the rocprof top-5 (past the
// 1 GiB / ~153us harness fills) so FETCH_SIZE / WRITE_SIZE of THIS kernel become
// visible, testing the write-allocate (RFO) amplification theory:
//   theory predicts FETCH_SIZE ~= 256 MiB * passes-that-miss, i.e. output lines
//   are fetched from HBM before being overwritten. Marginal pass cost separates
//   expand (store-path) cost from compute cost.

constexpr int S_ = 1024;
constexpr int D_ = 64;
constexpr int BQ = 64;     // rows per block = 4 waves x 16
constexpr int CP = 272;    // f32 pitch (1088 B)

typedef __attribute__((ext_vector_type(8))) short short8;   // 8 bf16 (MFMA A/B frag)
typedef __attribute__((ext_vector_type(4))) float f32x4;    // MFMA C/D frag

__device__ __forceinline__ unsigned short f2bf(float x) {
  unsigned u = __float_as_uint(x);
  return (unsigned short)((u + 0x7fffu + ((u >> 16) & 1u)) >> 16);  // RNE
}
__device__ __forceinline__ f32x4 ld4(const float* p) {
  return *reinterpret_cast<const f32x4*>(p);
}
__device__ __forceinline__ short8 pack8(f32x4 a, f32x4 b) {
  short8 r;
  r[0] = (short)f2bf(a.x); r[1] = (short)f2bf(a.y);
  r[2] = (short)f2bf(a.z); r[3] = (short)f2bf(a.w);
  r[4] = (short)f2bf(b.x); r[5] = (short)f2bf(b.y);
  r[6] = (short)f2bf(b.z); r[7] = (short)f2bf(b.w);
  return r;
}

__global__ __launch_bounds__(256, 2)
void relpos_v10(const float* __restrict__ tensor,
                const float* __restrict__ relk,
                const float* __restrict__ bias,
                float* __restrict__ out) {
  __shared__ __align__(16) float c_lds[BQ * CP];   // 69632 B -> 2 blocks/CU

  const int tid  = threadIdx.x;
  const int lane = tid & 63;
  const int w    = tid >> 6;
  const int bh   = blockIdx.x >> 4;
  const int s0   = (blockIdx.x & 15) * BQ;
  const int h    = bh & 15;
  const int l15  = lane & 15;
  const int l4   = lane >> 4;
  const int r0   = 16 * w + l4 * 4;

  // ---- A fragments ----
  const float* xrow = tensor + ((size_t)(bh * S_ + s0 + 16 * w + l15)) * D_ + l4 * 8;
  short8 a0 = pack8(ld4(xrow),      ld4(xrow + 4));
  short8 a1 = pack8(ld4(xrow + 32), ld4(xrow + 36));
  const float bv = bias[h];

  // ---- compute f32 c-table with margins (bias baked in) ----
#pragma unroll 2
  for (int nt = 0; nt < 17; ++nt) {
    const int vcol = 16 * nt + l15;
    const int erow = vcol > 256 ? 256 : vcol;
    const float* ep = relk + (size_t)erow * D_ + l4 * 8;
    short8 b0 = pack8(ld4(ep),      ld4(ep + 4));
    short8 b1 = pack8(ld4(ep + 32), ld4(ep + 36));
    f32x4 acc = {0.f, 0.f, 0.f, 0.f};
    acc = __builtin_amdgcn_mfma_f32_16x16x32_bf16(a0, b0, acc, 0, 0, 0);
    acc = __builtin_amdgcn_mfma_f32_16x16x32_bf16(a1, b1, acc, 0, 0, 0);
    // D mapping [m89]: col = l15 (= v-16nt), row = r0 + i
    if (vcol <= 256) {
#pragma unroll
      for (int i = 0; i < 4; ++i)
        c_lds[(r0 + i) * CP + i + 4 + vcol] = acc[i] + bv;   // pad = (s&3) = i
    }
    if (l15 == 0 && nt == 0) {
#pragma unroll
      for (int i = 0; i < 4; ++i) {
        const float cv = acc[i] + bv;
        for (int j = 0; j <= i + 3; ++j) c_lds[(r0 + i) * CP + j] = cv;
      }
    }
    if (l15 == 0 && nt == 16) {
#pragma unroll
      for (int i = 0; i < 4; ++i) {
        const float cv = acc[i] + bv;
        for (int j = i + 261; j < CP; ++j) c_lds[(r0 + i) * CP + j] = cv;
      }
    }
  }
  __syncthreads();

  // ---- expand: 3 identical idempotent passes (DIAGNOSTIC) ----
  float* obase = out + ((size_t)bh * S_ + s0) * (size_t)S_;
  const int mc = 132 - s0;
  for (int pass = 0; pass < 3; ++pass) {
#pragma unroll 8
    for (int it = 0; it < 64; ++it) {
      const int idx = it * 256 + tid;
      const int rl  = idx >> 8;
      const int t0  = (idx & 255) << 2;
      int m0 = t0 + (rl & 3) + mc - rl;
      m0 = m0 < 0 ? 0 : (m0 > 264 ? 264 : m0);
      const f32x4 o = *reinterpret_cast<const f32x4*>(&c_lds[rl * CP + m0]);
      *reinterpret_cast<f32x4*>(&obase[(size_t)idx * 4]) = o;
    }
    asm volatile("" ::: "memory");   // keep the passes' stores distinct/ordered
  }
}

extern "C" void kernel_launch(void* const* d_in, const int* in_sizes, int n_in,
                              void* d_out, int out_size, void* d_ws, size_t ws_size,
                              hipStream_t stream) {
  const float* tensor = (const float*)d_in[0];
  const float* relk   = (const float*)d_in[1];
  // d_in[2] = rel_values_emb (unused in forward), d_in[4] = max_relative_position (=128)
  const float* bias   = (const float*)d_in[3];
  float* out          = (float*)d_out;

  const int B = 4, H = 16;
  dim3 grid(B * H * (S_ / BQ));   // 1024 blocks, 2/CU
  dim3 block(256);
  relpos_v10<<<grid, block, 0, stream>>>(tensor, relk, bias, out);
}

// Round 11
// 67.304 us; speedup vs baseline: 2.0531x; 2.0531x over previous
//
#include <hip/hip_runtime.h>

// RelativeAttentionPositions: out[b,h,s,t] = dot(tensor[b,h,s,:], E[clip(t-s,-128,128)+128,:]) + bias[h]
// B=4 H=16 S=1024 D=64 MAX_REL=128 VOCAB=257.
// v11 = v9 (f32 c-table, zero-unpack ds_read_b128->store expand) with the output
// stores issued as inline-asm global_store_dwordx4 sc0 sc1 (system-scope write).
// Theory: out is exactly L3-sized; plain stores thrash L3 (alloc + dirty-evict
// round-trip serializes at ~3.9 TB/s — the invariant wall of v2..v9). Scope-bypass
// stores skip MALL allocation entirely -> store stream goes to HBM like the 6.9 TB/s
// fill. v10 diagnostic: issue path sustains 8.3 TB/s (marginal pass 32us), so the
// only thing between us and ~45-55us is the L3 round-trip.

constexpr int S_ = 1024;
constexpr int D_ = 64;
constexpr int BQ = 64;     // rows per block = 4 waves x 16
constexpr int CP = 272;    // f32 pitch (1088 B)

typedef __attribute__((ext_vector_type(8))) short short8;   // 8 bf16 (MFMA A/B frag)
typedef __attribute__((ext_vector_type(4))) float f32x4;    // MFMA C/D frag

__device__ __forceinline__ unsigned short f2bf(float x) {
  unsigned u = __float_as_uint(x);
  return (unsigned short)((u + 0x7fffu + ((u >> 16) & 1u)) >> 16);  // RNE
}
__device__ __forceinline__ f32x4 ld4(const float* p) {
  return *reinterpret_cast<const f32x4*>(p);
}
__device__ __forceinline__ short8 pack8(f32x4 a, f32x4 b) {
  short8 r;
  r[0] = (short)f2bf(a.x); r[1] = (short)f2bf(a.y);
  r[2] = (short)f2bf(a.z); r[3] = (short)f2bf(a.w);
  r[4] = (short)f2bf(b.x); r[5] = (short)f2bf(b.y);
  r[6] = (short)f2bf(b.z); r[7] = (short)f2bf(b.w);
  return r;
}
// system-scope store: bypass L2/MALL allocation (sc0 sc1), straight toward HBM.
__device__ __forceinline__ void store_sys(float* __restrict__ base, unsigned byte_off, f32x4 v) {
  asm volatile("global_store_dwordx4 %0, %1, %2 sc0 sc1"
               :: "v"(byte_off), "v"(v), "s"(base)
               : "memory");
}

__global__ __launch_bounds__(256, 2)
void relpos_v11(const float* __restrict__ tensor,
                const float* __restrict__ relk,
                const float* __restrict__ bias,
                float* __restrict__ out) {
  __shared__ __align__(16) float c_lds[BQ * CP];   // 69632 B -> 2 blocks/CU

  const int tid  = threadIdx.x;
  const int lane = tid & 63;
  const int w    = tid >> 6;
  const int bh   = blockIdx.x >> 4;
  const int s0   = (blockIdx.x & 15) * BQ;
  const int h    = bh & 15;
  const int l15  = lane & 15;
  const int l4   = lane >> 4;
  const int r0   = 16 * w + l4 * 4;

  // ---- A fragments: rows s0+16w+l15, k = l4*8 (+0 / +32) ----
  const float* xrow = tensor + ((size_t)(bh * S_ + s0 + 16 * w + l15)) * D_ + l4 * 8;
  short8 a0 = pack8(ld4(xrow),      ld4(xrow + 4));
  short8 a1 = pack8(ld4(xrow + 32), ld4(xrow + 36));
  const float bv = bias[h];

  // ---- compute f32 c-table with margins (bias baked in) ----
#pragma unroll 2
  for (int nt = 0; nt < 17; ++nt) {
    const int vcol = 16 * nt + l15;
    const int erow = vcol > 256 ? 256 : vcol;
    const float* ep = relk + (size_t)erow * D_ + l4 * 8;
    short8 b0 = pack8(ld4(ep),      ld4(ep + 4));
    short8 b1 = pack8(ld4(ep + 32), ld4(ep + 36));
    f32x4 acc = {0.f, 0.f, 0.f, 0.f};
    acc = __builtin_amdgcn_mfma_f32_16x16x32_bf16(a0, b0, acc, 0, 0, 0);
    acc = __builtin_amdgcn_mfma_f32_16x16x32_bf16(a1, b1, acc, 0, 0, 0);
    // D mapping [m89]: col = l15 (= v-16nt), row = r0 + i
    if (vcol <= 256) {
#pragma unroll
      for (int i = 0; i < 4; ++i)
        c_lds[(r0 + i) * CP + i + 4 + vcol] = acc[i] + bv;   // pad = (s&3) = i
    }
    if (l15 == 0 && nt == 0) {        // lane holds c[row][0] -> left margin [0, pad+3]
#pragma unroll
      for (int i = 0; i < 4; ++i) {
        const float cv = acc[i] + bv;
        for (int j = 0; j <= i + 3; ++j) c_lds[(r0 + i) * CP + j] = cv;
      }
    }
    if (l15 == 0 && nt == 16) {       // lane holds c[row][256] -> right margin [pad+261, 271]
#pragma unroll
      for (int i = 0; i < 4; ++i) {
        const float cv = acc[i] + bv;
        for (int j = i + 261; j < CP; ++j) c_lds[(r0 + i) * CP + j] = cv;
      }
    }
  }
  __syncthreads();

  // ---- expand: ds_read_b128 -> system-scope store (no L3 allocate) ----
  float* obase = out + ((size_t)bh * S_ + s0) * (size_t)S_;
  const int mc = 132 - s0;
#pragma unroll 8
  for (int it = 0; it < 64; ++it) {
    const int idx = it * 256 + tid;   // 16-B chunk index within block region
    const int rl  = idx >> 8;
    const int t0  = (idx & 255) << 2;
    int m0 = t0 + (rl & 3) + mc - rl;
    m0 = m0 < 0 ? 0 : (m0 > 264 ? 264 : m0);   // stays ==0 mod 4
    const f32x4 o = *reinterpret_cast<const f32x4*>(&c_lds[rl * CP + m0]);
    store_sys(obase, (unsigned)idx * 16u, o);
  }
}

extern "C" void kernel_launch(void* const* d_in, const int* in_sizes, int n_in,
                              void* d_out, int out_size, void* d_ws, size_t ws_size,
                              hipStream_t stream) {
  const float* tensor = (const float*)d_in[0];
  const float* relk   = (const float*)d_in[1];
  // d_in[2] = rel_values_emb (unused in forward), d_in[4] = max_relative_position (=128)
  const float* bias   = (const float*)d_in[3];
  float* out          = (float*)d_out;

  const int B = 4, H = 16;
  dim3 grid(B * H * (S_ / BQ));   // 1024 blocks, 2/CU
  dim3 block(256);
  relpos_v11<<<grid, block, 0, stream>>>(tensor, relk, bias, out);
}